// Round 9
// baseline (172.651 us; speedup 1.0000x reference)
//
#include <hip/hip_runtime.h>
#include <hip/hip_bf16.h>
#include <cstdint>

// Problem constants
#define NB   32      // batch
#define NC   256     // z channels
#define NE   128     // embed dim
#define NS   256     // H*W pixels per batch
#define NV   4096    // vocab
#define NP   8192    // total pixels
#define NSPLIT 8     // vocab splits (512 codes each)

typedef unsigned short ushort_t;
typedef __attribute__((ext_vector_type(8))) short bf16x8;
typedef __attribute__((ext_vector_type(8))) unsigned short us8;
typedef __attribute__((ext_vector_type(4))) float f32x4;

__device__ __forceinline__ ushort_t f2bf(float f) {
    __hip_bfloat16 h = __float2bfloat16(f);
    ushort_t u; __builtin_memcpy(&u, &h, 2); return u;
}
__device__ __forceinline__ unsigned asu(float f) { unsigned u; __builtin_memcpy(&u,&f,4); return u; }
__device__ __forceinline__ float    asf(unsigned u) { float f; __builtin_memcpy(&f,&u,4); return f; }

// ---------------------------------------------------------------------------
// K0: pack emb hi-bf16 into Bpack (MFMA B-frag order) + cnorm. (Validated.)
// Bpack (ushort units): [(G*4 + ks)*512 + L*8 + j],
//   element = emb[code = G*16 + (L&15)][k = ks*32 + (L>>4)*8 + j]
// ---------------------------------------------------------------------------
__global__ __launch_bounds__(256) void pack_emb(
    const float* __restrict__ emb, ushort_t* __restrict__ Bpack,
    float* __restrict__ cnorm)
{
    const int t = threadIdx.x;
    const int v     = blockIdx.x * 32 + (t >> 3);
    const int chunk = t & 7;
    const float4* rp = (const float4*)(emb + (size_t)v * NE + chunk * 16);
    float4 x0 = rp[0], x1 = rp[1], x2 = rp[2], x3 = rp[3];
    float xs[16] = { x0.x, x0.y, x0.z, x0.w, x1.x, x1.y, x1.z, x1.w,
                     x2.x, x2.y, x2.z, x2.w, x3.x, x3.y, x3.z, x3.w };
    us8 h0, h1;
    float nn = 0.f;
#pragma unroll
    for (int j = 0; j < 8; j++) {
        nn = fmaf(xs[j], xs[j], nn);
        h0[j] = f2bf(xs[j]);
    }
#pragma unroll
    for (int j = 0; j < 8; j++) {
        nn = fmaf(xs[8 + j], xs[8 + j], nn);
        h1[j] = f2bf(xs[8 + j]);
    }
    nn += __shfl_xor(nn, 1);
    nn += __shfl_xor(nn, 2);
    nn += __shfl_xor(nn, 4);
    if (chunk == 0) cnorm[v] = 0.5f * nn;

    const int G  = v >> 4;
    const int ks = chunk >> 1;
    const int q0 = (chunk & 1) * 2;
    const int L0 = (v & 15) | (q0 << 4);
    const int L1 = (v & 15) | ((q0 + 1) << 4);
    *(us8*)(Bpack + ((size_t)G * 4 + ks) * 512 + L0 * 8) = h0;
    *(us8*)(Bpack + ((size_t)G * 4 + ks) * 512 + L1 * 8) = h1;
}

// ---------------------------------------------------------------------------
// K_main v3c: identical to round-8 v3b EXCEPT the occupancy attribute.
// Rounds 7+8 lesson: __launch_bounds__(1024, N) is ignored by hipcc's
// allocator heuristic for 1024-thread workgroups — both (1024,4) and
// (1024,1) produced a 64-VGPR budget (8 waves/SIMD target) and ~30 MB of
// scratch spill (WRITE_SIZE 46 MB vs 16 legit). Native clang attributes pin
// it: amdgpu_waves_per_eu(4,4) -> budget = 512/4 = 128 VGPRs, which fits
// the measured ~88-100-reg P3 working set (round 5: VGPR 88, no spill).
// 256 blocks x 1024 threads (16 waves, 1 block/CU, 4 waves/SIMD).
// ---------------------------------------------------------------------------
#define ZE_STR   32
#define ZL_STR   132
#define ZE_OFF   0           // 256*32*4 = 32768 (dead after P2)
#define R1_OFF   0           // 4*64*33*4 = 33792 (aliases ze union region)
#define ZL_OFF   33792       // 32*132*4 = 16896  (eg aliases after P4)
#define R2_OFF   50688       // 33792
#define T4B_OFF  84480       // 4*32*4*4*4 = 8192
#define CAND_OFF 92672       // 8*32*4*4 = 4096
#define TOK_OFF  96768       // 32*4 = 128
#define SM_SIZE  96896

__global__
__attribute__((amdgpu_flat_work_group_size(1024, 1024), amdgpu_waves_per_eu(4, 4)))
void vq_main(
    const float* __restrict__ z_e, const float* __restrict__ pre_w,
    const float* __restrict__ pre_b, const float* __restrict__ emb,
    const float* __restrict__ post_w, const float* __restrict__ post_b,
    const ushort_t* __restrict__ Bpack, const float* __restrict__ cnorm,
    float* __restrict__ out_z, float* __restrict__ out_zq,
    float* __restrict__ out_rec)
{
    __shared__ __align__(16) char smraw[SM_SIZE];
    float* ze   = (float*)(smraw + ZE_OFF);
    float* r1   = (float*)(smraw + R1_OFF);
    float* r2   = (float*)(smraw + R2_OFF);
    float* t4b  = (float*)(smraw + T4B_OFF);
    float* zl   = (float*)(smraw + ZL_OFF);
    float* eg   = (float*)(smraw + ZL_OFF);    // alias, used after P4
    int*   cand = (int*)(smraw + CAND_OFF);
    int*   tok  = (int*)(smraw + TOK_OFF);

    const int t  = threadIdx.x;
    const int b  = blockIdx.x >> 3;
    const int s0 = (blockIdx.x & 7) * 32;

    // ================= P1: stage z_e[b, :, s0..s0+32] (float4) ========
    for (int idx = t; idx < NC * 8; idx += 1024) {
        int c = idx >> 3, q = idx & 7;
        *(float4*)&ze[c * ZE_STR + q * 4] =
            *(const float4*)(z_e + ((size_t)b * NC + c) * NS + s0 + q * 4);
    }
    __syncthreads();

    // ================= P2: z-GEMM (f32) ===============================
    {
        const int pg = t >> 7;       // px quad 0..7
        const int e  = t & 127;      // embed row
        const float* wr = pre_w + (size_t)e * NC;
        float a0 = 0.f, a1 = 0.f, a2 = 0.f, a3 = 0.f;
#pragma unroll 2
        for (int c = 0; c < NC; c += 4) {
            float4 w4 = *(const float4*)(wr + c);
            float4 z4;
            z4 = *(const float4*)&ze[(c + 0) * ZE_STR + pg * 4];
            a0 = fmaf(w4.x, z4.x, a0); a1 = fmaf(w4.x, z4.y, a1);
            a2 = fmaf(w4.x, z4.z, a2); a3 = fmaf(w4.x, z4.w, a3);
            z4 = *(const float4*)&ze[(c + 1) * ZE_STR + pg * 4];
            a0 = fmaf(w4.y, z4.x, a0); a1 = fmaf(w4.y, z4.y, a1);
            a2 = fmaf(w4.y, z4.z, a2); a3 = fmaf(w4.y, z4.w, a3);
            z4 = *(const float4*)&ze[(c + 2) * ZE_STR + pg * 4];
            a0 = fmaf(w4.z, z4.x, a0); a1 = fmaf(w4.z, z4.y, a1);
            a2 = fmaf(w4.z, z4.z, a2); a3 = fmaf(w4.z, z4.w, a3);
            z4 = *(const float4*)&ze[(c + 3) * ZE_STR + pg * 4];
            a0 = fmaf(w4.w, z4.x, a0); a1 = fmaf(w4.w, z4.y, a1);
            a2 = fmaf(w4.w, z4.z, a2); a3 = fmaf(w4.w, z4.w, a3);
        }
        const float bias = pre_b[e];
        a0 += bias; a1 += bias; a2 += bias; a3 += bias;
        zl[(pg * 4 + 0) * ZL_STR + e] = a0;
        zl[(pg * 4 + 1) * ZL_STR + e] = a1;
        zl[(pg * 4 + 2) * ZL_STR + e] = a2;
        zl[(pg * 4 + 3) * ZL_STR + e] = a3;
        float4 o = { a0, a1, a2, a3 };
        *(float4*)(out_z + ((size_t)b * NE + e) * NS + s0 + pg * 4) = o;
    }
    __syncthreads();

    // ================= P3: MFMA scoring + top-4/split =================
    const int wave = t >> 6, lane = t & 63;
    const int am = lane & 15, aq = lane >> 4;

    // A-fragments (validated packing, mt=2 over 32 rows)
    bf16x8 ah[2][4];
#pragma unroll
    for (int mt = 0; mt < 2; mt++)
#pragma unroll
        for (int ks = 0; ks < 4; ks++) {
            const unsigned* src = (const unsigned*)(zl + (mt * 16 + am) * ZL_STR + ks * 32 + aq * 8);
            union { unsigned u[4]; bf16x8 v; } pk;
#pragma unroll
            for (int pr = 0; pr < 4; pr++)
                pk.u[pr] = (src[2 * pr + 1] & 0xFFFF0000u) | (src[2 * pr] >> 16);
            ah[mt][ks] = pk.v;
        }

    const int wq = wave >> 2;      // split within quad (4 in flight)
    const int wv = wave & 3;       // plays validated kernel's "wave"

    for (int sp = 0; sp < NSPLIT; sp += 4) {
        const int split = sp + wq;
        const int Gbase = split * 32 + wv * 8;
        float cn[8];
#pragma unroll
        for (int cgi = 0; cgi < 8; cgi++)
            cn[cgi] = cnorm[(Gbase + cgi) * 16 + am];

        float b1v[8], b2v[8];
#pragma unroll
        for (int i = 0; i < 8; i++) { b1v[i] = -1e30f; b2v[i] = -1e30f; }

        bf16x8 bh[4], bhn[4];
#pragma unroll
        for (int ks = 0; ks < 4; ks++)
            bh[ks] = *(const bf16x8*)(Bpack + ((size_t)Gbase * 4 + ks) * 512 + lane * 8);

        for (int cgi = 0; cgi < 8; cgi++) {
            if (cgi < 7) {
#pragma unroll
                for (int ks = 0; ks < 4; ks++)
                    bhn[ks] = *(const bf16x8*)(Bpack + ((size_t)(Gbase + cgi + 1) * 4 + ks) * 512 + lane * 8);
            }
            f32x4 acc[2];
#pragma unroll
            for (int mt = 0; mt < 2; mt++) acc[mt] = (f32x4){0.f, 0.f, 0.f, 0.f};
#pragma unroll
            for (int ks = 0; ks < 4; ks++)
#pragma unroll
                for (int mt = 0; mt < 2; mt++)
                    acc[mt] = __builtin_amdgcn_mfma_f32_16x16x32_bf16(ah[mt][ks], bh[ks], acc[mt], 0, 0, 0);

#pragma unroll
            for (int mt = 0; mt < 2; mt++)
#pragma unroll
                for (int reg = 0; reg < 4; reg++) {
                    const int si = mt * 4 + reg;
                    float sc = acc[mt][reg] - cn[cgi];
                    float ev = asf((asu(sc) & ~7u) | (unsigned)cgi);
                    b2v[si] = fmaxf(b2v[si], fminf(ev, b1v[si]));
                    b1v[si] = fmaxf(b1v[si], ev);
                }
#pragma unroll
            for (int ks = 0; ks < 4; ks++) bh[ks] = bhn[ks];
        }

        const int slot = wv * 16 + am;
#pragma unroll
        for (int mt = 0; mt < 2; mt++)
#pragma unroll
            for (int reg = 0; reg < 4; reg++) {
                int px = mt * 16 + aq * 4 + reg;
                r1[(wq * 64 + slot) * 33 + px] = b1v[mt * 4 + reg];
                r2[(wq * 64 + slot) * 33 + px] = b2v[mt * 4 + reg];
            }
        __syncthreads();

        if (t < 512) {
            const int wq2 = t >> 7, rem = t & 127;
            const int px = rem >> 2, ch = rem & 3;
            float t1 = -1e30f, t2 = -1e30f, t3 = -1e30f, t4 = -1e30f;
            for (int i = 0; i < 16; i++) {
                int sl = ch * 16 + i;
#pragma unroll
                for (int e = 0; e < 2; e++) {
                    float raw = e ? r2[(wq2 * 64 + sl) * 33 + px]
                                  : r1[(wq2 * 64 + sl) * 33 + px];
                    unsigned vb = asu(raw);
                    float v = asf((vb & ~511u) | ((unsigned)sl << 3) | (vb & 7u));
                    t4 = fmaxf(t4, fminf(v, t3));
                    t3 = fmaxf(t3, fminf(v, t2));
                    t2 = fmaxf(t2, fminf(v, t1));
                    t1 = fmaxf(t1, v);
                }
            }
            float* dst = t4b + ((wq2 * 32 + px) * 4 + ch) * 4;
            dst[0] = t1; dst[1] = t2; dst[2] = t3; dst[3] = t4;
        }
        __syncthreads();

        if (t < 128) {
            const int wq2 = t >> 5, px = t & 31;
            float u1 = -1e30f, u2 = -1e30f, u3 = -1e30f, u4 = -1e30f;
            for (int ch = 0; ch < 4; ch++) {
#pragma unroll
                for (int j = 0; j < 4; j++) {
                    float v = t4b[((wq2 * 32 + px) * 4 + ch) * 4 + j];
                    u4 = fmaxf(u4, fminf(v, u3));
                    u3 = fmaxf(u3, fminf(v, u2));
                    u2 = fmaxf(u2, fminf(v, u1));
                    u1 = fmaxf(u1, v);
                }
            }
            const int spw = sp + wq2;
            float uu[4] = { u1, u2, u3, u4 };
#pragma unroll
            for (int j = 0; j < 4; j++) {
                unsigned bits = asu(uu[j]) & 511u;
                int w = (int)(bits >> 7), res = (int)((bits >> 3) & 15u), cg = (int)(bits & 7u);
                cand[(spw * 32 + px) * 4 + j] = spw * 512 + (w * 8 + cg) * 16 + res;
            }
        }
        __syncthreads();
    }

    // ================= P4: exact f64 rescore (1 cand/thread) ==========
    {
        const int il = t >> 5;   // px 0..31
        const int cc = t & 31;   // candidate 0..31
        const int split = cc >> 2, slot = cc & 3;
        const int idx = cand[(split * 32 + il) * 4 + slot];
        const float* er = emb + (size_t)idx * NE;
        const float* zr = zl + il * ZL_STR;

        double d0 = 0.0, d1 = 0.0, d2 = 0.0, d3 = 0.0;
        double n0 = 0.0, n1 = 0.0, n2 = 0.0, n3 = 0.0;
#pragma unroll
        for (int k = 0; k < NE; k += 16) {
            float4 e0 = *(const float4*)(er + k + 0);
            float4 e1 = *(const float4*)(er + k + 4);
            float4 e2 = *(const float4*)(er + k + 8);
            float4 e3 = *(const float4*)(er + k + 12);
            float4 z0 = *(const float4*)(zr + k + 0);
            float4 z1 = *(const float4*)(zr + k + 4);
            float4 z2 = *(const float4*)(zr + k + 8);
            float4 z3 = *(const float4*)(zr + k + 12);
            d0 += (double)z0.x * e0.x; d0 += (double)z0.y * e0.y;
            d0 += (double)z0.z * e0.z; d0 += (double)z0.w * e0.w;
            d1 += (double)z1.x * e1.x; d1 += (double)z1.y * e1.y;
            d1 += (double)z1.z * e1.z; d1 += (double)z1.w * e1.w;
            d2 += (double)z2.x * e2.x; d2 += (double)z2.y * e2.y;
            d2 += (double)z2.z * e2.z; d2 += (double)z2.w * e2.w;
            d3 += (double)z3.x * e3.x; d3 += (double)z3.y * e3.y;
            d3 += (double)z3.z * e3.z; d3 += (double)z3.w * e3.w;
            n0 += (double)e0.x * e0.x; n0 += (double)e0.y * e0.y;
            n0 += (double)e0.z * e0.z; n0 += (double)e0.w * e0.w;
            n1 += (double)e1.x * e1.x; n1 += (double)e1.y * e1.y;
            n1 += (double)e1.z * e1.z; n1 += (double)e1.w * e1.w;
            n2 += (double)e2.x * e2.x; n2 += (double)e2.y * e2.y;
            n2 += (double)e2.z * e2.z; n2 += (double)e2.w * e2.w;
            n3 += (double)e3.x * e3.x; n3 += (double)e3.y * e3.y;
            n3 += (double)e3.z * e3.z; n3 += (double)e3.w * e3.w;
        }
        double bs = ((d0 + d1) + (d2 + d3)) - 0.5 * ((n0 + n1) + (n2 + n3));
        int bi = idx;
#pragma unroll
        for (int m = 1; m <= 16; m <<= 1) {
            double osc = __shfl_xor(bs, m);
            int    obi = __shfl_xor(bi, m);
            if (osc > bs || (osc == bs && obi < bi)) { bs = osc; bi = obi; }
        }
        if (cc == 0) tok[il] = bi;
    }
    __syncthreads();

    // ================= P5: gather z_q -> eg (aliases zl) + out_zq =====
    {
        const int px = t >> 5, eq = t & 31;   // 1024 = 32px x 32 quads
        *(float4*)&eg[px * ZL_STR + eq * 4] =
            *(const float4*)(emb + (size_t)tok[px] * NE + eq * 4);
    }
    __syncthreads();
    for (int idx = t; idx < NE * 32; idx += 1024) {
        int e = idx >> 5, i = idx & 31;
        out_zq[((size_t)b * NE + e) * NS + s0 + i] = eg[i * ZL_STR + e];
    }
    // no barrier needed: P6 only reads eg (already fenced above)

    // ================= P6: post_conv ==================================
    {
        const int c  = t & 255;
        const int ph = t >> 8;          // px group: 0..3 -> 8 px each
        const int pb = ph * 8;
        const float* wr = post_w + (size_t)c * NE;
        const float bias = post_b[c];
        float a0 = 0.f, a1 = 0.f, a2 = 0.f, a3 = 0.f;
        float a4 = 0.f, a5 = 0.f, a6 = 0.f, a7 = 0.f;
#pragma unroll 4
        for (int k = 0; k < NE; k += 4) {
            float4 w4 = *(const float4*)(wr + k);
            float4 q;
            q = *(const float4*)&eg[(pb + 0) * ZL_STR + k];
            a0 = fmaf(w4.x, q.x, fmaf(w4.y, q.y, fmaf(w4.z, q.z, fmaf(w4.w, q.w, a0))));
            q = *(const float4*)&eg[(pb + 1) * ZL_STR + k];
            a1 = fmaf(w4.x, q.x, fmaf(w4.y, q.y, fmaf(w4.z, q.z, fmaf(w4.w, q.w, a1))));
            q = *(const float4*)&eg[(pb + 2) * ZL_STR + k];
            a2 = fmaf(w4.x, q.x, fmaf(w4.y, q.y, fmaf(w4.z, q.z, fmaf(w4.w, q.w, a2))));
            q = *(const float4*)&eg[(pb + 3) * ZL_STR + k];
            a3 = fmaf(w4.x, q.x, fmaf(w4.y, q.y, fmaf(w4.z, q.z, fmaf(w4.w, q.w, a3))));
            q = *(const float4*)&eg[(pb + 4) * ZL_STR + k];
            a4 = fmaf(w4.x, q.x, fmaf(w4.y, q.y, fmaf(w4.z, q.z, fmaf(w4.w, q.w, a4))));
            q = *(const float4*)&eg[(pb + 5) * ZL_STR + k];
            a5 = fmaf(w4.x, q.x, fmaf(w4.y, q.y, fmaf(w4.z, q.z, fmaf(w4.w, q.w, a5))));
            q = *(const float4*)&eg[(pb + 6) * ZL_STR + k];
            a6 = fmaf(w4.x, q.x, fmaf(w4.y, q.y, fmaf(w4.z, q.z, fmaf(w4.w, q.w, a6))));
            q = *(const float4*)&eg[(pb + 7) * ZL_STR + k];
            a7 = fmaf(w4.x, q.x, fmaf(w4.y, q.y, fmaf(w4.z, q.z, fmaf(w4.w, q.w, a7))));
        }
        float4 lo = { a0 + bias, a1 + bias, a2 + bias, a3 + bias };
        float4 hi = { a4 + bias, a5 + bias, a6 + bias, a7 + bias };
        float* dst = out_rec + ((size_t)b * NC + c) * NS + s0 + pb;
        *(float4*)(dst + 0) = lo;
        *(float4*)(dst + 4) = hi;
    }
}

// ---------------------------------------------------------------------------
extern "C" void kernel_launch(void* const* d_in, const int* in_sizes, int n_in,
                              void* d_out, int out_size, void* d_ws, size_t ws_size,
                              hipStream_t stream)
{
    const float* z_e    = (const float*)d_in[0];
    const float* pre_w  = (const float*)d_in[1];
    const float* pre_b  = (const float*)d_in[2];
    const float* emb    = (const float*)d_in[3];
    const float* post_w = (const float*)d_in[4];
    const float* post_b = (const float*)d_in[5];

    // d_out: fp32 x 4194304 = (z 1048576 | z_q 1048576 | rec 2097152)
    float* out     = (float*)d_out;
    float* out_z   = out;
    float* out_zq  = out + 1048576;
    float* out_rec = out + 2097152;

    // Scratch: Bpack 1 MB + cnorm 16 KB in d_ws (fallback: rec head; the
    // d_ws path has always been taken in this harness, ws_size >= 2 MB).
    const size_t SZ_BPACK = (size_t)256 * 4 * 512 * 2;            // 1 MB
    const size_t SZ_CNORM = (size_t)NV * 4;                       // 16 KB
    const size_t NEED = SZ_BPACK + SZ_CNORM;
    char* scr = (ws_size >= NEED) ? (char*)d_ws : (char*)out_rec;
    ushort_t* Bpack = (ushort_t*)scr;
    float*    cnorm = (float*)(scr + SZ_BPACK);

    pack_emb<<<dim3(128), 256,  0, stream>>>(emb, Bpack, cnorm);
    vq_main <<<dim3(256), 1024, 0, stream>>>(z_e, pre_w, pre_b, emb,
                                             post_w, post_b, Bpack, cnorm,
                                             out_z, out_zq, out_rec);
}

// Round 10
// 164.722 us; speedup vs baseline: 1.0481x; 1.0481x over previous
//
#include <hip/hip_runtime.h>
#include <hip/hip_bf16.h>
#include <cstdint>

// Problem constants
#define NB   32      // batch
#define NC   256     // z channels
#define NE   128     // embed dim
#define NS   256     // H*W pixels per batch
#define NV   4096    // vocab
#define NP   8192    // total pixels
#define NSPLIT 8     // vocab splits (512 codes each)

typedef unsigned short ushort_t;
typedef __attribute__((ext_vector_type(8))) short bf16x8;
typedef __attribute__((ext_vector_type(8))) unsigned short us8;
typedef __attribute__((ext_vector_type(4))) float f32x4;

__device__ __forceinline__ ushort_t f2bf(float f) {
    __hip_bfloat16 h = __float2bfloat16(f);
    ushort_t u; __builtin_memcpy(&u, &h, 2); return u;
}
__device__ __forceinline__ unsigned asu(float f) { unsigned u; __builtin_memcpy(&u,&f,4); return u; }
__device__ __forceinline__ float    asf(unsigned u) { float f; __builtin_memcpy(&f,&u,4); return f; }

// ---------------------------------------------------------------------------
// K0: pack emb hi-bf16 into Bpack (MFMA B-frag order) + cnorm. (Validated.)
// Bpack (ushort units): [(G*4 + ks)*512 + L*8 + j],
//   element = emb[code = G*16 + (L&15)][k = ks*32 + (L>>4)*8 + j]
// ---------------------------------------------------------------------------
__global__ __launch_bounds__(256) void pack_emb(
    const float* __restrict__ emb, ushort_t* __restrict__ Bpack,
    float* __restrict__ cnorm)
{
    const int t = threadIdx.x;
    const int v     = blockIdx.x * 32 + (t >> 3);
    const int chunk = t & 7;
    const float4* rp = (const float4*)(emb + (size_t)v * NE + chunk * 16);
    float4 x0 = rp[0], x1 = rp[1], x2 = rp[2], x3 = rp[3];
    float xs[16] = { x0.x, x0.y, x0.z, x0.w, x1.x, x1.y, x1.z, x1.w,
                     x2.x, x2.y, x2.z, x2.w, x3.x, x3.y, x3.z, x3.w };
    us8 h0, h1;
    float nn = 0.f;
#pragma unroll
    for (int j = 0; j < 8; j++) {
        nn = fmaf(xs[j], xs[j], nn);
        h0[j] = f2bf(xs[j]);
    }
#pragma unroll
    for (int j = 0; j < 8; j++) {
        nn = fmaf(xs[8 + j], xs[8 + j], nn);
        h1[j] = f2bf(xs[8 + j]);
    }
    nn += __shfl_xor(nn, 1);
    nn += __shfl_xor(nn, 2);
    nn += __shfl_xor(nn, 4);
    if (chunk == 0) cnorm[v] = 0.5f * nn;

    const int G  = v >> 4;
    const int ks = chunk >> 1;
    const int q0 = (chunk & 1) * 2;
    const int L0 = (v & 15) | (q0 << 4);
    const int L1 = (v & 15) | ((q0 + 1) << 4);
    *(us8*)(Bpack + ((size_t)G * 4 + ks) * 512 + L0 * 8) = h0;
    *(us8*)(Bpack + ((size_t)G * 4 + ks) * 512 + L1 * 8) = h1;
}

// ---------------------------------------------------------------------------
// K_main v4: 256 blocks x 1024 threads (16 waves, 1 block/CU, 4 waves/SIMD).
// Rounds 7-9 lesson: the allocator gives this 1024-thread kernel 64 arch
// VGPRs no matter what launch_bounds / amdgpu_waves_per_eu say. So P3 is
// redesigned to FIT 64: wave = (split ws, px-half wh); each wave scores its
// split's full 512 codes (32 cgi iters, mt gone -> ah[4] = 16 regs, bh[4] =
// 16, no prefetch, cnorm loaded in-loop). Working set ~58 regs. Trade-offs:
// B-traffic 2 MB/block (L2), stage-1 encode keeps 5-bit cgi (32-ulp
// truncation; same 512-ulp final encode; exact f64 rescore absorbs it).
// Top-4 reduction is now a single 256-thread stage over 16 am-slots.
// P1/P2/P4/P5/P6 identical to round 9.
// ---------------------------------------------------------------------------
#define ZE_STR   32
#define ZL_STR   132
#define ZE_OFF   0           // 256*32*4 = 32768 (dead after P2)
#define ZL_OFF   32768       // 32*132*4 = 16896 (eg aliases after P4)
#define R1_OFF   49664       // 128*33*4 = 16896
#define R2_OFF   66560       // 16896
#define CAND_OFF 83456       // 8*32*4*4 = 4096
#define TOK_OFF  87552       // 32*4 = 128
#define SM_SIZE  87680

__global__ __launch_bounds__(1024) void vq_main(
    const float* __restrict__ z_e, const float* __restrict__ pre_w,
    const float* __restrict__ pre_b, const float* __restrict__ emb,
    const float* __restrict__ post_w, const float* __restrict__ post_b,
    const ushort_t* __restrict__ Bpack, const float* __restrict__ cnorm,
    float* __restrict__ out_z, float* __restrict__ out_zq,
    float* __restrict__ out_rec)
{
    __shared__ __align__(16) char smraw[SM_SIZE];
    float* ze   = (float*)(smraw + ZE_OFF);
    float* zl   = (float*)(smraw + ZL_OFF);
    float* eg   = (float*)(smraw + ZL_OFF);    // alias, used after P4
    float* r1   = (float*)(smraw + R1_OFF);
    float* r2   = (float*)(smraw + R2_OFF);
    int*   cand = (int*)(smraw + CAND_OFF);
    int*   tok  = (int*)(smraw + TOK_OFF);

    const int t  = threadIdx.x;
    const int b  = blockIdx.x >> 3;
    const int s0 = (blockIdx.x & 7) * 32;

    // ================= P1: stage z_e[b, :, s0..s0+32] (float4) ========
    for (int idx = t; idx < NC * 8; idx += 1024) {
        int c = idx >> 3, q = idx & 7;
        *(float4*)&ze[c * ZE_STR + q * 4] =
            *(const float4*)(z_e + ((size_t)b * NC + c) * NS + s0 + q * 4);
    }
    __syncthreads();

    // ================= P2: z-GEMM (f32) ===============================
    {
        const int pg = t >> 7;       // px quad 0..7
        const int e  = t & 127;      // embed row
        const float* wr = pre_w + (size_t)e * NC;
        float a0 = 0.f, a1 = 0.f, a2 = 0.f, a3 = 0.f;
#pragma unroll 2
        for (int c = 0; c < NC; c += 4) {
            float4 w4 = *(const float4*)(wr + c);
            float4 z4;
            z4 = *(const float4*)&ze[(c + 0) * ZE_STR + pg * 4];
            a0 = fmaf(w4.x, z4.x, a0); a1 = fmaf(w4.x, z4.y, a1);
            a2 = fmaf(w4.x, z4.z, a2); a3 = fmaf(w4.x, z4.w, a3);
            z4 = *(const float4*)&ze[(c + 1) * ZE_STR + pg * 4];
            a0 = fmaf(w4.y, z4.x, a0); a1 = fmaf(w4.y, z4.y, a1);
            a2 = fmaf(w4.y, z4.z, a2); a3 = fmaf(w4.y, z4.w, a3);
            z4 = *(const float4*)&ze[(c + 2) * ZE_STR + pg * 4];
            a0 = fmaf(w4.z, z4.x, a0); a1 = fmaf(w4.z, z4.y, a1);
            a2 = fmaf(w4.z, z4.z, a2); a3 = fmaf(w4.z, z4.w, a3);
            z4 = *(const float4*)&ze[(c + 3) * ZE_STR + pg * 4];
            a0 = fmaf(w4.w, z4.x, a0); a1 = fmaf(w4.w, z4.y, a1);
            a2 = fmaf(w4.w, z4.z, a2); a3 = fmaf(w4.w, z4.w, a3);
        }
        const float bias = pre_b[e];
        a0 += bias; a1 += bias; a2 += bias; a3 += bias;
        zl[(pg * 4 + 0) * ZL_STR + e] = a0;
        zl[(pg * 4 + 1) * ZL_STR + e] = a1;
        zl[(pg * 4 + 2) * ZL_STR + e] = a2;
        zl[(pg * 4 + 3) * ZL_STR + e] = a3;
        float4 o = { a0, a1, a2, a3 };
        *(float4*)(out_z + ((size_t)b * NE + e) * NS + s0 + pg * 4) = o;
    }
    __syncthreads();

    // ================= P3: MFMA scoring, wave = (split, px-half) ======
    {
        const int wave = t >> 6, lane = t & 63;
        const int am = lane & 15, aq = lane >> 4;
        const int ws = wave >> 1;      // split 0..7
        const int wh = wave & 1;       // px half 0..1

        // A-fragments for rows wh*16 + am (validated packing, mt dropped)
        bf16x8 ah[4];
#pragma unroll
        for (int ks = 0; ks < 4; ks++) {
            const unsigned* src = (const unsigned*)(zl + (wh * 16 + am) * ZL_STR + ks * 32 + aq * 8);
            union { unsigned u[4]; bf16x8 v; } pk;
#pragma unroll
            for (int pr = 0; pr < 4; pr++)
                pk.u[pr] = (src[2 * pr + 1] & 0xFFFF0000u) | (src[2 * pr] >> 16);
            ah[ks] = pk.v;
        }

        float b1v[4], b2v[4];
#pragma unroll
        for (int i = 0; i < 4; i++) { b1v[i] = -1e30f; b2v[i] = -1e30f; }

        const int Gbase = ws * 32;     // first code-group of this split
        const ushort_t* bp = Bpack + (size_t)Gbase * 4 * 512 + lane * 8;

        for (int cgi = 0; cgi < 32; cgi++) {
            bf16x8 bh[4];
#pragma unroll
            for (int ks = 0; ks < 4; ks++)
                bh[ks] = *(const bf16x8*)(bp + (size_t)(cgi * 4 + ks) * 512);
            float cnv = cnorm[(Gbase + cgi) * 16 + am];

            f32x4 acc = (f32x4){0.f, 0.f, 0.f, 0.f};
#pragma unroll
            for (int ks = 0; ks < 4; ks++)
                acc = __builtin_amdgcn_mfma_f32_16x16x32_bf16(ah[ks], bh[ks], acc, 0, 0, 0);

#pragma unroll
            for (int reg = 0; reg < 4; reg++) {
                float sc = acc[reg] - cnv;
                float ev = asf((asu(sc) & ~31u) | (unsigned)cgi);
                b2v[reg] = fmaxf(b2v[reg], fminf(ev, b1v[reg]));
                b1v[reg] = fmaxf(b1v[reg], ev);
            }
        }

#pragma unroll
        for (int reg = 0; reg < 4; reg++) {
            const int px = wh * 16 + aq * 4 + reg;
            r1[(ws * 16 + am) * 33 + px] = b1v[reg];
            r2[(ws * 16 + am) * 33 + px] = b2v[reg];
        }
    }
    __syncthreads();

    // ---- top-4 per (split, px): one stage, 256 threads ----
    if (t < 256) {
        const int sp = t >> 5, px = t & 31;
        float u1 = -1e30f, u2 = -1e30f, u3 = -1e30f, u4 = -1e30f;
        for (int a = 0; a < 16; a++) {
#pragma unroll
            for (int e = 0; e < 2; e++) {
                float raw = e ? r2[(sp * 16 + a) * 33 + px]
                              : r1[(sp * 16 + a) * 33 + px];
                unsigned vb = asu(raw);
                float v = asf((vb & ~511u) | ((unsigned)a << 5) | (vb & 31u));
                u4 = fmaxf(u4, fminf(v, u3));
                u3 = fmaxf(u3, fminf(v, u2));
                u2 = fmaxf(u2, fminf(v, u1));
                u1 = fmaxf(u1, v);
            }
        }
        float uu[4] = { u1, u2, u3, u4 };
#pragma unroll
        for (int j = 0; j < 4; j++) {
            unsigned bits = asu(uu[j]) & 511u;
            int cg = (int)(bits & 31u), res = (int)((bits >> 5) & 15u);
            cand[(sp * 32 + px) * 4 + j] = sp * 512 + cg * 16 + res;
        }
    }
    __syncthreads();

    // ================= P4: exact f64 rescore (1 cand/thread) ==========
    {
        const int il = t >> 5;   // px 0..31
        const int cc = t & 31;   // candidate 0..31
        const int split = cc >> 2, slot = cc & 3;
        const int idx = cand[(split * 32 + il) * 4 + slot];
        const float* er = emb + (size_t)idx * NE;
        const float* zr = zl + il * ZL_STR;

        double d0 = 0.0, d1 = 0.0, d2 = 0.0, d3 = 0.0;
        double n0 = 0.0, n1 = 0.0, n2 = 0.0, n3 = 0.0;
#pragma unroll
        for (int k = 0; k < NE; k += 16) {
            float4 e0 = *(const float4*)(er + k + 0);
            float4 e1 = *(const float4*)(er + k + 4);
            float4 e2 = *(const float4*)(er + k + 8);
            float4 e3 = *(const float4*)(er + k + 12);
            float4 z0 = *(const float4*)(zr + k + 0);
            float4 z1 = *(const float4*)(zr + k + 4);
            float4 z2 = *(const float4*)(zr + k + 8);
            float4 z3 = *(const float4*)(zr + k + 12);
            d0 += (double)z0.x * e0.x; d0 += (double)z0.y * e0.y;
            d0 += (double)z0.z * e0.z; d0 += (double)z0.w * e0.w;
            d1 += (double)z1.x * e1.x; d1 += (double)z1.y * e1.y;
            d1 += (double)z1.z * e1.z; d1 += (double)z1.w * e1.w;
            d2 += (double)z2.x * e2.x; d2 += (double)z2.y * e2.y;
            d2 += (double)z2.z * e2.z; d2 += (double)z2.w * e2.w;
            d3 += (double)z3.x * e3.x; d3 += (double)z3.y * e3.y;
            d3 += (double)z3.z * e3.z; d3 += (double)z3.w * e3.w;
            n0 += (double)e0.x * e0.x; n0 += (double)e0.y * e0.y;
            n0 += (double)e0.z * e0.z; n0 += (double)e0.w * e0.w;
            n1 += (double)e1.x * e1.x; n1 += (double)e1.y * e1.y;
            n1 += (double)e1.z * e1.z; n1 += (double)e1.w * e1.w;
            n2 += (double)e2.x * e2.x; n2 += (double)e2.y * e2.y;
            n2 += (double)e2.z * e2.z; n2 += (double)e2.w * e2.w;
            n3 += (double)e3.x * e3.x; n3 += (double)e3.y * e3.y;
            n3 += (double)e3.z * e3.z; n3 += (double)e3.w * e3.w;
        }
        double bs = ((d0 + d1) + (d2 + d3)) - 0.5 * ((n0 + n1) + (n2 + n3));
        int bi = idx;
#pragma unroll
        for (int m = 1; m <= 16; m <<= 1) {
            double osc = __shfl_xor(bs, m);
            int    obi = __shfl_xor(bi, m);
            if (osc > bs || (osc == bs && obi < bi)) { bs = osc; bi = obi; }
        }
        if (cc == 0) tok[il] = bi;
    }
    __syncthreads();

    // ================= P5: gather z_q -> eg (aliases zl) + out_zq =====
    {
        const int px = t >> 5, eq = t & 31;   // 1024 = 32px x 32 quads
        *(float4*)&eg[px * ZL_STR + eq * 4] =
            *(const float4*)(emb + (size_t)tok[px] * NE + eq * 4);
    }
    __syncthreads();
    for (int idx = t; idx < NE * 32; idx += 1024) {
        int e = idx >> 5, i = idx & 31;
        out_zq[((size_t)b * NE + e) * NS + s0 + i] = eg[i * ZL_STR + e];
    }
    // no barrier needed: P6 only reads eg (already fenced above)

    // ================= P6: post_conv ==================================
    {
        const int c  = t & 255;
        const int ph = t >> 8;          // px group: 0..3 -> 8 px each
        const int pb = ph * 8;
        const float* wr = post_w + (size_t)c * NE;
        const float bias = post_b[c];
        float a0 = 0.f, a1 = 0.f, a2 = 0.f, a3 = 0.f;
        float a4 = 0.f, a5 = 0.f, a6 = 0.f, a7 = 0.f;
#pragma unroll 4
        for (int k = 0; k < NE; k += 4) {
            float4 w4 = *(const float4*)(wr + k);
            float4 q;
            q = *(const float4*)&eg[(pb + 0) * ZL_STR + k];
            a0 = fmaf(w4.x, q.x, fmaf(w4.y, q.y, fmaf(w4.z, q.z, fmaf(w4.w, q.w, a0))));
            q = *(const float4*)&eg[(pb + 1) * ZL_STR + k];
            a1 = fmaf(w4.x, q.x, fmaf(w4.y, q.y, fmaf(w4.z, q.z, fmaf(w4.w, q.w, a1))));
            q = *(const float4*)&eg[(pb + 2) * ZL_STR + k];
            a2 = fmaf(w4.x, q.x, fmaf(w4.y, q.y, fmaf(w4.z, q.z, fmaf(w4.w, q.w, a2))));
            q = *(const float4*)&eg[(pb + 3) * ZL_STR + k];
            a3 = fmaf(w4.x, q.x, fmaf(w4.y, q.y, fmaf(w4.z, q.z, fmaf(w4.w, q.w, a3))));
            q = *(const float4*)&eg[(pb + 4) * ZL_STR + k];
            a4 = fmaf(w4.x, q.x, fmaf(w4.y, q.y, fmaf(w4.z, q.z, fmaf(w4.w, q.w, a4))));
            q = *(const float4*)&eg[(pb + 5) * ZL_STR + k];
            a5 = fmaf(w4.x, q.x, fmaf(w4.y, q.y, fmaf(w4.z, q.z, fmaf(w4.w, q.w, a5))));
            q = *(const float4*)&eg[(pb + 6) * ZL_STR + k];
            a6 = fmaf(w4.x, q.x, fmaf(w4.y, q.y, fmaf(w4.z, q.z, fmaf(w4.w, q.w, a6))));
            q = *(const float4*)&eg[(pb + 7) * ZL_STR + k];
            a7 = fmaf(w4.x, q.x, fmaf(w4.y, q.y, fmaf(w4.z, q.z, fmaf(w4.w, q.w, a7))));
        }
        float4 lo = { a0 + bias, a1 + bias, a2 + bias, a3 + bias };
        float4 hi = { a4 + bias, a5 + bias, a6 + bias, a7 + bias };
        float* dst = out_rec + ((size_t)b * NC + c) * NS + s0 + pb;
        *(float4*)(dst + 0) = lo;
        *(float4*)(dst + 4) = hi;
    }
}

// ---------------------------------------------------------------------------
extern "C" void kernel_launch(void* const* d_in, const int* in_sizes, int n_in,
                              void* d_out, int out_size, void* d_ws, size_t ws_size,
                              hipStream_t stream)
{
    const float* z_e    = (const float*)d_in[0];
    const float* pre_w  = (const float*)d_in[1];
    const float* pre_b  = (const float*)d_in[2];
    const float* emb    = (const float*)d_in[3];
    const float* post_w = (const float*)d_in[4];
    const float* post_b = (const float*)d_in[5];

    // d_out: fp32 x 4194304 = (z 1048576 | z_q 1048576 | rec 2097152)
    float* out     = (float*)d_out;
    float* out_z   = out;
    float* out_zq  = out + 1048576;
    float* out_rec = out + 2097152;

    // Scratch: Bpack 1 MB + cnorm 16 KB in d_ws (fallback: rec head; the
    // d_ws path has always been taken in this harness, ws_size >= 2 MB).
    const size_t SZ_BPACK = (size_t)256 * 4 * 512 * 2;            // 1 MB
    const size_t SZ_CNORM = (size_t)NV * 4;                       // 16 KB
    const size_t NEED = SZ_BPACK + SZ_CNORM;
    char* scr = (ws_size >= NEED) ? (char*)d_ws : (char*)out_rec;
    ushort_t* Bpack = (ushort_t*)scr;
    float*    cnorm = (float*)(scr + SZ_BPACK);

    pack_emb<<<dim3(128), 256,  0, stream>>>(emb, Bpack, cnorm);
    vq_main <<<dim3(256), 1024, 0, stream>>>(z_e, pre_w, pre_b, emb,
                                             post_w, post_b, Bpack, cnorm,
                                             out_z, out_zq, out_rec);
}

// Round 11
// 146.414 us; speedup vs baseline: 1.1792x; 1.1250x over previous
//
#include <hip/hip_runtime.h>
#include <hip/hip_bf16.h>
#include <cstdint>

// Problem constants
#define NB   32      // batch
#define NC   256     // z channels
#define NE   128     // embed dim
#define NS   256     // H*W pixels per batch
#define NV   4096    // vocab
#define NP   8192    // total pixels
#define NSPLIT 8     // vocab splits (512 codes each)

typedef unsigned short ushort_t;
typedef __attribute__((ext_vector_type(8))) short bf16x8;
typedef __attribute__((ext_vector_type(8))) unsigned short us8;
typedef __attribute__((ext_vector_type(4))) float f32x4;

__device__ __forceinline__ ushort_t f2bf(float f) {
    __hip_bfloat16 h = __float2bfloat16(f);
    ushort_t u; __builtin_memcpy(&u, &h, 2); return u;
}
__device__ __forceinline__ unsigned asu(float f) { unsigned u; __builtin_memcpy(&u,&f,4); return u; }
__device__ __forceinline__ float    asf(unsigned u) { float f; __builtin_memcpy(&f,&u,4); return f; }

// ---------------------------------------------------------------------------
// K0: pack emb hi-bf16 into Bpack (MFMA B-frag order) + cnorm. (Validated.)
// Bpack (ushort units): [(G*4 + ks)*512 + L*8 + j],
//   element = emb[code = G*16 + (L&15)][k = ks*32 + (L>>4)*8 + j]
// ---------------------------------------------------------------------------
__global__ __launch_bounds__(256) void pack_emb(
    const float* __restrict__ emb, ushort_t* __restrict__ Bpack,
    float* __restrict__ cnorm)
{
    const int t = threadIdx.x;
    const int v     = blockIdx.x * 32 + (t >> 3);
    const int chunk = t & 7;
    const float4* rp = (const float4*)(emb + (size_t)v * NE + chunk * 16);
    float4 x0 = rp[0], x1 = rp[1], x2 = rp[2], x3 = rp[3];
    float xs[16] = { x0.x, x0.y, x0.z, x0.w, x1.x, x1.y, x1.z, x1.w,
                     x2.x, x2.y, x2.z, x2.w, x3.x, x3.y, x3.z, x3.w };
    us8 h0, h1;
    float nn = 0.f;
#pragma unroll
    for (int j = 0; j < 8; j++) {
        nn = fmaf(xs[j], xs[j], nn);
        h0[j] = f2bf(xs[j]);
    }
#pragma unroll
    for (int j = 0; j < 8; j++) {
        nn = fmaf(xs[8 + j], xs[8 + j], nn);
        h1[j] = f2bf(xs[8 + j]);
    }
    nn += __shfl_xor(nn, 1);
    nn += __shfl_xor(nn, 2);
    nn += __shfl_xor(nn, 4);
    if (chunk == 0) cnorm[v] = 0.5f * nn;

    const int G  = v >> 4;
    const int ks = chunk >> 1;
    const int q0 = (chunk & 1) * 2;
    const int L0 = (v & 15) | (q0 << 4);
    const int L1 = (v & 15) | ((q0 + 1) << 4);
    *(us8*)(Bpack + ((size_t)G * 4 + ks) * 512 + L0 * 8) = h0;
    *(us8*)(Bpack + ((size_t)G * 4 + ks) * 512 + L1 * 8) = h1;
}

// ---------------------------------------------------------------------------
// K_main v5: exact round-5 kernel (the proven 83 µs / 144.4 µs config:
// 256 blocks x 512 threads, 88 VGPR no-spill, 32 px/block) with ONE change:
// P4 processes its two candidates INTERLEAVED in a single k-loop (shared z
// loads, 8 independent f64 chains, depth 128 -> 32, 3x load ILP) instead of
// two serial full-k passes. Rounds 6-10 lesson: every other shape (more
// blocks, 1024 threads) loses to this one — 1024-thread workgroups get a
// hard 64-VGPR budget from the allocator and serialize on load latency.
//   P1 stage z_e tile (ze[256][36])
//   P2 z-GEMM f32 -> zl[32][132] + out_z
//   P3 MFMA scoring, 2 splits in flight, mt=2, bhn prefetch (validated)
//   P4 f64 rescore, interleaved 2 cand/thread, 16-lane shfl argmax
//   P5 gather z_q -> eg (aliases zl) + out_zq
//   P6 post_conv (c = t&255, 2 passes x 8 px)
// ---------------------------------------------------------------------------
#define ZE_STR  36
#define ZL_STR  132
#define ZE_OFF  0            // 256*36*4 = 36864
#define R1_OFF  0            // 2*64*33*4 = 16896  (aliases ze, dead after P2)
#define R2_OFF  16896        // 16896
#define ZL_OFF  36864        // 32*132*4 = 16896   (eg aliases after P4)
#define T4B_OFF 53760        // 2*32*4*4*4 = 4096
#define CAND_OFF 57856       // 8*32*4*4 = 4096
#define TOK_OFF 61952        // 32*4 = 128
#define SM_SIZE 62080

__global__ __launch_bounds__(512, 2) void vq_main(
    const float* __restrict__ z_e, const float* __restrict__ pre_w,
    const float* __restrict__ pre_b, const float* __restrict__ emb,
    const float* __restrict__ post_w, const float* __restrict__ post_b,
    const ushort_t* __restrict__ Bpack, const float* __restrict__ cnorm,
    float* __restrict__ out_z, float* __restrict__ out_zq,
    float* __restrict__ out_rec)
{
    __shared__ __align__(16) char smraw[SM_SIZE];
    float* ze   = (float*)(smraw + ZE_OFF);
    float* r1   = (float*)(smraw + R1_OFF);
    float* r2   = (float*)(smraw + R2_OFF);
    float* zl   = (float*)(smraw + ZL_OFF);
    float* eg   = (float*)(smraw + ZL_OFF);    // alias, used after P4
    float* t4b  = (float*)(smraw + T4B_OFF);
    int*   cand = (int*)(smraw + CAND_OFF);
    int*   tok  = (int*)(smraw + TOK_OFF);

    const int t  = threadIdx.x;
    const int b  = blockIdx.x >> 3;
    const int s0 = (blockIdx.x & 7) * 32;

    // ================= P1: stage z_e[b, :, s0..s0+32] =================
    for (int idx = t; idx < NC * 32; idx += 512) {
        int c = idx >> 5, i = idx & 31;
        ze[c * ZE_STR + i] = z_e[((size_t)b * NC + c) * NS + s0 + i];
    }
    __syncthreads();

    // ================= P2: z-GEMM (f32) ===============================
    {
        const int pg = t >> 7;       // px group of 8
        const int e  = t & 127;      // embed row
        const float* wr = pre_w + (size_t)e * NC;
        float a0 = 0.f, a1 = 0.f, a2 = 0.f, a3 = 0.f;
        float a4 = 0.f, a5 = 0.f, a6 = 0.f, a7 = 0.f;
#pragma unroll 2
        for (int c = 0; c < NC; c += 4) {
            float4 w4 = *(const float4*)(wr + c);
            float4 za, zb;
            za = *(const float4*)&ze[(c + 0) * ZE_STR + pg * 8];
            zb = *(const float4*)&ze[(c + 0) * ZE_STR + pg * 8 + 4];
            a0 = fmaf(w4.x, za.x, a0); a1 = fmaf(w4.x, za.y, a1);
            a2 = fmaf(w4.x, za.z, a2); a3 = fmaf(w4.x, za.w, a3);
            a4 = fmaf(w4.x, zb.x, a4); a5 = fmaf(w4.x, zb.y, a5);
            a6 = fmaf(w4.x, zb.z, a6); a7 = fmaf(w4.x, zb.w, a7);
            za = *(const float4*)&ze[(c + 1) * ZE_STR + pg * 8];
            zb = *(const float4*)&ze[(c + 1) * ZE_STR + pg * 8 + 4];
            a0 = fmaf(w4.y, za.x, a0); a1 = fmaf(w4.y, za.y, a1);
            a2 = fmaf(w4.y, za.z, a2); a3 = fmaf(w4.y, za.w, a3);
            a4 = fmaf(w4.y, zb.x, a4); a5 = fmaf(w4.y, zb.y, a5);
            a6 = fmaf(w4.y, zb.z, a6); a7 = fmaf(w4.y, zb.w, a7);
            za = *(const float4*)&ze[(c + 2) * ZE_STR + pg * 8];
            zb = *(const float4*)&ze[(c + 2) * ZE_STR + pg * 8 + 4];
            a0 = fmaf(w4.z, za.x, a0); a1 = fmaf(w4.z, za.y, a1);
            a2 = fmaf(w4.z, za.z, a2); a3 = fmaf(w4.z, za.w, a3);
            a4 = fmaf(w4.z, zb.x, a4); a5 = fmaf(w4.z, zb.y, a5);
            a6 = fmaf(w4.z, zb.z, a6); a7 = fmaf(w4.z, zb.w, a7);
            za = *(const float4*)&ze[(c + 3) * ZE_STR + pg * 8];
            zb = *(const float4*)&ze[(c + 3) * ZE_STR + pg * 8 + 4];
            a0 = fmaf(w4.w, za.x, a0); a1 = fmaf(w4.w, za.y, a1);
            a2 = fmaf(w4.w, za.z, a2); a3 = fmaf(w4.w, za.w, a3);
            a4 = fmaf(w4.w, zb.x, a4); a5 = fmaf(w4.w, zb.y, a5);
            a6 = fmaf(w4.w, zb.z, a6); a7 = fmaf(w4.w, zb.w, a7);
        }
        const float bias = pre_b[e];
        a0 += bias; a1 += bias; a2 += bias; a3 += bias;
        a4 += bias; a5 += bias; a6 += bias; a7 += bias;
        // zl[px][e]
        zl[(pg * 8 + 0) * ZL_STR + e] = a0;
        zl[(pg * 8 + 1) * ZL_STR + e] = a1;
        zl[(pg * 8 + 2) * ZL_STR + e] = a2;
        zl[(pg * 8 + 3) * ZL_STR + e] = a3;
        zl[(pg * 8 + 4) * ZL_STR + e] = a4;
        zl[(pg * 8 + 5) * ZL_STR + e] = a5;
        zl[(pg * 8 + 6) * ZL_STR + e] = a6;
        zl[(pg * 8 + 7) * ZL_STR + e] = a7;
        // out_z, 32B contiguous per thread
        float4 lo = { a0, a1, a2, a3 };
        float4 hi = { a4, a5, a6, a7 };
        float* dst = out_z + ((size_t)b * NE + e) * NS + s0 + pg * 8;
        *(float4*)(dst + 0) = lo;
        *(float4*)(dst + 4) = hi;
    }
    __syncthreads();

    // ================= P3: MFMA scoring + top-4/split =================
    const int wave = t >> 6, lane = t & 63;
    const int am = lane & 15, aq = lane >> 4;

    // A-fragments (identical packing to validated score_mfma, mt=2)
    bf16x8 ah[2][4];
#pragma unroll
    for (int mt = 0; mt < 2; mt++)
#pragma unroll
        for (int ks = 0; ks < 4; ks++) {
            const unsigned* src = (const unsigned*)(zl + (mt * 16 + am) * ZL_STR + ks * 32 + aq * 8);
            union { unsigned u[4]; bf16x8 v; } pk;
#pragma unroll
            for (int pr = 0; pr < 4; pr++)
                pk.u[pr] = (src[2 * pr + 1] & 0xFFFF0000u) | (src[2 * pr] >> 16);
            ah[mt][ks] = pk.v;
        }

    const int wq = wave >> 2;      // split half within pair
    const int wv = wave & 3;       // plays validated kernel's "wave"

    for (int sp = 0; sp < NSPLIT; sp += 2) {
        const int split = sp + wq;
        const int Gbase = split * 32 + wv * 8;
        float cn[8];
#pragma unroll
        for (int cgi = 0; cgi < 8; cgi++)
            cn[cgi] = cnorm[(Gbase + cgi) * 16 + am];

        float b1v[8], b2v[8];
#pragma unroll
        for (int i = 0; i < 8; i++) { b1v[i] = -1e30f; b2v[i] = -1e30f; }

        bf16x8 bh[4], bhn[4];
#pragma unroll
        for (int ks = 0; ks < 4; ks++)
            bh[ks] = *(const bf16x8*)(Bpack + ((size_t)Gbase * 4 + ks) * 512 + lane * 8);

        for (int cgi = 0; cgi < 8; cgi++) {
            if (cgi < 7) {
#pragma unroll
                for (int ks = 0; ks < 4; ks++)
                    bhn[ks] = *(const bf16x8*)(Bpack + ((size_t)(Gbase + cgi + 1) * 4 + ks) * 512 + lane * 8);
            }
            f32x4 acc[2];
#pragma unroll
            for (int mt = 0; mt < 2; mt++) acc[mt] = (f32x4){0.f, 0.f, 0.f, 0.f};
#pragma unroll
            for (int ks = 0; ks < 4; ks++)
#pragma unroll
                for (int mt = 0; mt < 2; mt++)
                    acc[mt] = __builtin_amdgcn_mfma_f32_16x16x32_bf16(ah[mt][ks], bh[ks], acc[mt], 0, 0, 0);

#pragma unroll
            for (int mt = 0; mt < 2; mt++)
#pragma unroll
                for (int reg = 0; reg < 4; reg++) {
                    const int si = mt * 4 + reg;
                    float sc = acc[mt][reg] - cn[cgi];
                    float ev = asf((asu(sc) & ~7u) | (unsigned)cgi);
                    b2v[si] = fmaxf(b2v[si], fminf(ev, b1v[si]));
                    b1v[si] = fmaxf(b1v[si], ev);
                }
#pragma unroll
            for (int ks = 0; ks < 4; ks++) bh[ks] = bhn[ks];
        }

        const int slot = wv * 16 + am;
#pragma unroll
        for (int mt = 0; mt < 2; mt++)
#pragma unroll
            for (int reg = 0; reg < 4; reg++) {
                int px = mt * 16 + aq * 4 + reg;
                r1[(wq * 64 + slot) * 33 + px] = b1v[mt * 4 + reg];
                r2[(wq * 64 + slot) * 33 + px] = b2v[mt * 4 + reg];
            }
        __syncthreads();

        if (t < 256) {
            const int wq2 = t >> 7, rem = t & 127;
            const int px = rem >> 2, ch = rem & 3;
            float t1 = -1e30f, t2 = -1e30f, t3 = -1e30f, t4 = -1e30f;
            for (int i = 0; i < 16; i++) {
                int sl = ch * 16 + i;
#pragma unroll
                for (int e = 0; e < 2; e++) {
                    float raw = e ? r2[(wq2 * 64 + sl) * 33 + px]
                                  : r1[(wq2 * 64 + sl) * 33 + px];
                    unsigned vb = asu(raw);
                    float v = asf((vb & ~511u) | ((unsigned)sl << 3) | (vb & 7u));
                    t4 = fmaxf(t4, fminf(v, t3));
                    t3 = fmaxf(t3, fminf(v, t2));
                    t2 = fmaxf(t2, fminf(v, t1));
                    t1 = fmaxf(t1, v);
                }
            }
            float* dst = t4b + ((wq2 * 32 + px) * 4 + ch) * 4;
            dst[0] = t1; dst[1] = t2; dst[2] = t3; dst[3] = t4;
        }
        __syncthreads();

        if (t < 64) {
            const int wq2 = t >> 5, px = t & 31;
            float u1 = -1e30f, u2 = -1e30f, u3 = -1e30f, u4 = -1e30f;
            for (int ch = 0; ch < 4; ch++) {
#pragma unroll
                for (int j = 0; j < 4; j++) {
                    float v = t4b[((wq2 * 32 + px) * 4 + ch) * 4 + j];
                    u4 = fmaxf(u4, fminf(v, u3));
                    u3 = fmaxf(u3, fminf(v, u2));
                    u2 = fmaxf(u2, fminf(v, u1));
                    u1 = fmaxf(u1, v);
                }
            }
            const int spw = sp + wq2;
            float uu[4] = { u1, u2, u3, u4 };
#pragma unroll
            for (int j = 0; j < 4; j++) {
                unsigned bits = asu(uu[j]) & 511u;
                int w = (int)(bits >> 7), res = (int)((bits >> 3) & 15u), cg = (int)(bits & 7u);
                cand[(spw * 32 + px) * 4 + j] = spw * 512 + (w * 8 + cg) * 16 + res;
            }
        }
        __syncthreads();
    }

    // ================= P4: f64 rescore, interleaved 2 cand/thread =====
    {
        const int il = t >> 4;   // px 0..31
        const int cc = t & 15;   // candidate pair 0..15
        const int c0 = cc * 2, c1 = cc * 2 + 1;
        const int idx0 = cand[((c0 >> 2) * 32 + il) * 4 + (c0 & 3)];
        const int idx1 = cand[((c1 >> 2) * 32 + il) * 4 + (c1 & 3)];
        const float* e0p = emb + (size_t)idx0 * NE;
        const float* e1p = emb + (size_t)idx1 * NE;
        const float* zr  = zl + il * ZL_STR;

        double da0 = 0.0, da1 = 0.0, na0 = 0.0, na1 = 0.0;
        double db0 = 0.0, db1 = 0.0, nb0 = 0.0, nb1 = 0.0;
#pragma unroll
        for (int k = 0; k < NE; k += 8) {
            float4 za = *(const float4*)(zr + k);
            float4 zb = *(const float4*)(zr + k + 4);
            float4 ea = *(const float4*)(e0p + k);
            float4 eb = *(const float4*)(e0p + k + 4);
            float4 fa = *(const float4*)(e1p + k);
            float4 fb = *(const float4*)(e1p + k + 4);
            da0 += (double)za.x * ea.x; da0 += (double)za.y * ea.y;
            da0 += (double)za.z * ea.z; da0 += (double)za.w * ea.w;
            da1 += (double)zb.x * eb.x; da1 += (double)zb.y * eb.y;
            da1 += (double)zb.z * eb.z; da1 += (double)zb.w * eb.w;
            na0 += (double)ea.x * ea.x; na0 += (double)ea.y * ea.y;
            na0 += (double)ea.z * ea.z; na0 += (double)ea.w * ea.w;
            na1 += (double)eb.x * eb.x; na1 += (double)eb.y * eb.y;
            na1 += (double)eb.z * eb.z; na1 += (double)eb.w * eb.w;
            db0 += (double)za.x * fa.x; db0 += (double)za.y * fa.y;
            db0 += (double)za.z * fa.z; db0 += (double)za.w * fa.w;
            db1 += (double)zb.x * fb.x; db1 += (double)zb.y * fb.y;
            db1 += (double)zb.z * fb.z; db1 += (double)zb.w * fb.w;
            nb0 += (double)fa.x * fa.x; nb0 += (double)fa.y * fa.y;
            nb0 += (double)fa.z * fa.z; nb0 += (double)fa.w * fa.w;
            nb1 += (double)fb.x * fb.x; nb1 += (double)fb.y * fb.y;
            nb1 += (double)fb.z * fb.z; nb1 += (double)fb.w * fb.w;
        }
        double s0 = (da0 + da1) - 0.5 * (na0 + na1);
        double s1 = (db0 + db1) - 0.5 * (nb0 + nb1);
        // pair-local pick, same rule as serial version (score, tie -> low idx)
        double bs; int bi;
        if (s1 > s0 || (s1 == s0 && idx1 < idx0)) { bs = s1; bi = idx1; }
        else                                       { bs = s0; bi = idx0; }
#pragma unroll
        for (int m = 1; m <= 8; m <<= 1) {
            double osc = __shfl_xor(bs, m);
            int    obi = __shfl_xor(bi, m);
            if (osc > bs || (osc == bs && obi < bi)) { bs = osc; bi = obi; }
        }
        if (cc == 0) tok[il] = bi;
    }
    __syncthreads();

    // ================= P5: gather z_q -> eg (aliases zl) + out_zq =====
    for (int idx = t; idx < 32 * 32; idx += 512) {      // 2 iters, float4
        int px = idx >> 5, eq = idx & 31;
        float4 v4 = *(const float4*)(emb + (size_t)tok[px] * NE + eq * 4);
        *(float4*)&eg[px * ZL_STR + eq * 4] = v4;
    }
    __syncthreads();
    for (int idx = t; idx < NE * 32; idx += 512) {      // 8 iters, coalesced
        int e = idx >> 5, i = idx & 31;
        out_zq[((size_t)b * NE + e) * NS + s0 + i] = eg[i * ZL_STR + e];
    }
    __syncthreads();

    // ================= P6: post_conv ==================================
    {
        const int c  = t & 255;
        const int ph = t >> 8;
        const float* wr = post_w + (size_t)c * NE;
        const float bias = post_b[c];
#pragma unroll
        for (int pass = 0; pass < 2; pass++) {
            const int pb = pass * 16 + ph * 8;
            float a0 = 0.f, a1 = 0.f, a2 = 0.f, a3 = 0.f;
            float a4 = 0.f, a5 = 0.f, a6 = 0.f, a7 = 0.f;
#pragma unroll 4
            for (int k = 0; k < NE; k += 4) {
                float4 w4 = *(const float4*)(wr + k);
                float4 q;
                q = *(const float4*)&eg[(pb + 0) * ZL_STR + k];
                a0 = fmaf(w4.x, q.x, fmaf(w4.y, q.y, fmaf(w4.z, q.z, fmaf(w4.w, q.w, a0))));
                q = *(const float4*)&eg[(pb + 1) * ZL_STR + k];
                a1 = fmaf(w4.x, q.x, fmaf(w4.y, q.y, fmaf(w4.z, q.z, fmaf(w4.w, q.w, a1))));
                q = *(const float4*)&eg[(pb + 2) * ZL_STR + k];
                a2 = fmaf(w4.x, q.x, fmaf(w4.y, q.y, fmaf(w4.z, q.z, fmaf(w4.w, q.w, a2))));
                q = *(const float4*)&eg[(pb + 3) * ZL_STR + k];
                a3 = fmaf(w4.x, q.x, fmaf(w4.y, q.y, fmaf(w4.z, q.z, fmaf(w4.w, q.w, a3))));
                q = *(const float4*)&eg[(pb + 4) * ZL_STR + k];
                a4 = fmaf(w4.x, q.x, fmaf(w4.y, q.y, fmaf(w4.z, q.z, fmaf(w4.w, q.w, a4))));
                q = *(const float4*)&eg[(pb + 5) * ZL_STR + k];
                a5 = fmaf(w4.x, q.x, fmaf(w4.y, q.y, fmaf(w4.z, q.z, fmaf(w4.w, q.w, a5))));
                q = *(const float4*)&eg[(pb + 6) * ZL_STR + k];
                a6 = fmaf(w4.x, q.x, fmaf(w4.y, q.y, fmaf(w4.z, q.z, fmaf(w4.w, q.w, a6))));
                q = *(const float4*)&eg[(pb + 7) * ZL_STR + k];
                a7 = fmaf(w4.x, q.x, fmaf(w4.y, q.y, fmaf(w4.z, q.z, fmaf(w4.w, q.w, a7))));
            }
            float4 lo = { a0 + bias, a1 + bias, a2 + bias, a3 + bias };
            float4 hi = { a4 + bias, a5 + bias, a6 + bias, a7 + bias };
            float* dst = out_rec + ((size_t)b * NC + c) * NS + s0 + pb;
            *(float4*)(dst + 0) = lo;
            *(float4*)(dst + 4) = hi;
        }
    }
}

// ---------------------------------------------------------------------------
extern "C" void kernel_launch(void* const* d_in, const int* in_sizes, int n_in,
                              void* d_out, int out_size, void* d_ws, size_t ws_size,
                              hipStream_t stream)
{
    const float* z_e    = (const float*)d_in[0];
    const float* pre_w  = (const float*)d_in[1];
    const float* pre_b  = (const float*)d_in[2];
    const float* emb    = (const float*)d_in[3];
    const float* post_w = (const float*)d_in[4];
    const float* post_b = (const float*)d_in[5];

    // d_out: fp32 x 4194304 = (z 1048576 | z_q 1048576 | rec 2097152)
    float* out     = (float*)d_out;
    float* out_z   = out;
    float* out_zq  = out + 1048576;
    float* out_rec = out + 2097152;

    // Scratch: Bpack 1 MB + cnorm 16 KB in d_ws (fallback: rec head; the
    // d_ws path has always been taken in this harness, ws_size >= 2 MB).
    const size_t SZ_BPACK = (size_t)256 * 4 * 512 * 2;            // 1 MB
    const size_t SZ_CNORM = (size_t)NV * 4;                       // 16 KB
    const size_t NEED = SZ_BPACK + SZ_CNORM;
    char* scr = (ws_size >= NEED) ? (char*)d_ws : (char*)out_rec;
    ushort_t* Bpack = (ushort_t*)scr;
    float*    cnorm = (float*)(scr + SZ_BPACK);

    pack_emb<<<dim3(128), 256, 0, stream>>>(emb, Bpack, cnorm);
    vq_main <<<dim3(256), 512, 0, stream>>>(z_e, pre_w, pre_b, emb,
                                            post_w, post_b, Bpack, cnorm,
                                            out_z, out_zq, out_rec);
}